// Round 13
// baseline (262.285 us; speedup 1.0000x reference)
//
#include <hip/hip_runtime.h>
#include <math.h>

typedef _Float16 f16;
typedef _Float16 f16x8 __attribute__((ext_vector_type(8)));
typedef _Float16 f16x4 __attribute__((ext_vector_type(4)));
typedef __fp16 fp16x2 __attribute__((ext_vector_type(2)));
typedef float f32x4 __attribute__((ext_vector_type(4)));
typedef float f32x16 __attribute__((ext_vector_type(16)));

#define NM 16384    // nodes (K of big GEMM)
#define NE 4096     // hyperedges
#define ND 300      // feature dim
#define DP 320      // padded feature dim
#define PS 1310720  // per-partial f16 elements (4096*320)

#define GLOAD_LDS16(gsrc, ldst)                                              \
  __builtin_amdgcn_global_load_lds(                                          \
      (__attribute__((address_space(1))) void*)(gsrc),                       \
      (__attribute__((address_space(3))) void*)(ldst), 16, 0, 0)

#define K2WAIT(N) asm volatile("s_waitcnt vmcnt(" #N ") lgkmcnt(0)" ::: "memory")
#define K2BAR()                                        \
  do {                                                 \
    asm volatile("" ::: "memory");                     \
    __builtin_amdgcn_s_barrier();                      \
    asm volatile("" ::: "memory");                     \
  } while (0)
#define K2BARW()                                       \
  do {                                                 \
    asm volatile("s_waitcnt lgkmcnt(0)" ::: "memory"); \
    __builtin_amdgcn_s_barrier();                      \
    asm volatile("" ::: "memory");                     \
  } while (0)

// ---------------------------------------------------------------- k01: X -> XT (f16, padded) + W_att^T -> f16
__global__ __launch_bounds__(256) void k01_prep(const float* __restrict__ X,
                                                const float* __restrict__ Watt,
                                                f16* __restrict__ XT,
                                                f16* __restrict__ WT) {
  __shared__ f16 tile[64][324];
  const int bx = blockIdx.x;
  if (bx < 256) {
    int m0 = bx * 64;
    for (int idx = threadIdx.x; idx < 64 * 80; idx += 256) {
      int m = idx / 80, q = idx % 80;
      int d = q * 4;
      float4 v = make_float4(0.f, 0.f, 0.f, 0.f);
      if (d < ND) v = *(const float4*)(X + (size_t)(m0 + m) * ND + d);
      tile[m][d] = (f16)v.x; tile[m][d + 1] = (f16)v.y;
      tile[m][d + 2] = (f16)v.z; tile[m][d + 3] = (f16)v.w;
    }
    __syncthreads();
    for (int idx = threadIdx.x; idx < DP * 8; idx += 256) {
      int d = idx >> 3, part = idx & 7;
      f16x8 hv;
#pragma unroll
      for (int i = 0; i < 8; ++i) hv[i] = tile[part * 8 + i][d];
      *(f16x8*)(XT + (size_t)d * NM + m0 + part * 8) = hv;
    }
  } else {
    int idx = (bx - 256) * 256 + threadIdx.x;
    if (idx < DP * DP) {
      int j = idx / DP, d = idx % DP;
      float v = (j < ND && d < ND) ? Watt[d * ND + j] : 0.f;
      WT[(size_t)j * DP + d] = (f16)v;
    }
  }
}

// ---------------------------------------------------------------- k2 v12: EF0 = inc^T @ X, 32x32x16 MFMA
// block 128e x 320j x BK32, 512 thr / 8 waves (4we x 2wj), wave 32e x 160j
// -> acc[5] = 80 AGPR, ~150 regs/wave -> 2 waves/SIMD (real latency hiding).
// grid 512 = 32 eb x 16 kb, xcd = kb&7. B-ring-3 + A-ring-2, implicit vmcnt.
// v12 fix: tail writes A(31) from rA1 (v11 wrote rA0 = A(30) -> wrong step 31).
// LDS: B @ 0/20480/40960 (320 rows x 64B); A @ 61440/69632 (128 rows x 64B)
__global__ __launch_bounds__(512, 2) void k2_bigmm(const float* __restrict__ inc,
                                                   const f16* __restrict__ XT,
                                                   f16* __restrict__ Zp) {
  __shared__ __align__(16) char lds[77824];
  const int t = threadIdx.x, lane = t & 63, wid = t >> 6;
  const int bx = blockIdx.x;
  const int kb = (bx & 7) | (((bx >> 3) & 1) << 3);
  const int eb = bx >> 4;
  const int e0 = eb * 128;
  const size_t kbase = (size_t)kb * 1024;
  f16* __restrict__ Zout = Zp + (size_t)kb * PS;

  const int we = wid >> 1, wj = wid & 1;
  const int l31 = lane & 31, oct = lane >> 5;
  int sl[2];
#pragma unroll
  for (int kk = 0; kk < 2; ++kk)
    sl[kk] = (((kk * 2 + oct) ^ ((l31 >> 1) & 3)) & 3) << 4;
  const int arow = (we * 32 + l31) * 64;
  const int brow = (wj * 160 + l31) * 64;
  // A staging: thread = (ae = t&127, kq = t>>7); 8 scalar k-loads, 1 uint4 write
  const int ae = t & 127, kq = t >> 7;
  const int wa = 61440 + ae * 64 + (((kq ^ ((ae >> 1) & 3)) & 3) << 4);
  const float* pA = inc + (kbase + kq * 8) * NE + e0 + ae;
  // B staging: 20 units of 16 rows; wave w -> units {w, 8+w, 16+w if w<4}
  const int bsw = 8 * ((lane & 3) ^ ((lane >> 3) & 3));
  const f16* pB0 = XT + (size_t)(wid * 16 + (lane >> 2)) * NM + kbase + bsw;
  const f16* pB1 = XT + (size_t)((8 + wid) * 16 + (lane >> 2)) * NM + kbase + bsw;
  const f16* pB2 = XT + (size_t)((16 + wid) * 16 + (lane >> 2)) * NM + kbase + bsw;

  float rA0[8], rA1[8];
  f32x16 acc[5];
#pragma unroll
  for (int f = 0; f < 5; ++f)
#pragma unroll
    for (int r = 0; r < 16; ++r) acc[f][r] = 0.f;

#define LOADA(R)                                                               \
  {                                                                            \
    _Pragma("unroll") for (int i = 0; i < 8; ++i)                              \
        R[i] = pA[(size_t)i * NE];                                             \
    pA += (size_t)32 * NE;                                                     \
  }
#define DMAB(S)                                                                \
  {                                                                            \
    GLOAD_LDS16(pB0, lds + (S)*20480 + wid * 1024);                            \
    GLOAD_LDS16(pB1, lds + (S)*20480 + (8 + wid) * 1024);                      \
    if (wid < 4) GLOAD_LDS16(pB2, lds + (S)*20480 + (16 + wid) * 1024);        \
    pB0 += 32; pB1 += 32; pB2 += 32;                                           \
  }
#define WRITEA(R, S)                                                           \
  {                                                                            \
    union { fp16x2 h; uint32_t u; } u_[4];                                     \
    _Pragma("unroll") for (int z = 0; z < 4; ++z)                              \
      u_[z].h = __builtin_amdgcn_cvt_pkrtz(R[2 * z], R[2 * z + 1]);            \
    *(uint4*)(lds + wa + (S)*8192) = make_uint4(u_[0].u, u_[1].u, u_[2].u, u_[3].u); \
  }
#define COMPUTE(BS, AS)                                                        \
  {                                                                            \
    __builtin_amdgcn_s_setprio(1);                                             \
    _Pragma("unroll") for (int kk = 0; kk < 2; ++kk) {                         \
      f16x8 a_ = *(const f16x8*)(lds + 61440 + (AS)*8192 + arow + sl[kk]);     \
      _Pragma("unroll") for (int f = 0; f < 5; ++f) {                          \
        f16x8 b_ = *(const f16x8*)(lds + (BS)*20480 + brow + f * 2048 + sl[kk]); \
        acc[f] = __builtin_amdgcn_mfma_f32_32x32x16_f16(a_, b_, acc[f], 0, 0, 0); \
      }                                                                        \
    }                                                                          \
    __builtin_amdgcn_s_setprio(0);                                             \
  }
// BODY(tt): stage B(tt+2), load A(tt+2), write A(tt+1); barrier; compute tt.
#define BODY(BSTG, BCMP, AW, AC, RL, RW)                                       \
  DMAB(BSTG);                                                                  \
  LOADA(RL);                                                                   \
  WRITEA(RW, AW); /* implicit vmcnt drains A(tt+1) => B(tt+1),B(tt) resident */\
  K2BARW();                                                                    \
  COMPUTE(BCMP, AC);                                                           \
  K2BAR();

  // prologue
  LOADA(rA0);        // A(0)
  DMAB(0);           // B(0)
  WRITEA(rA0, 0);    // A(0) -> Abuf0 (implicit wait A(0))
  LOADA(rA1);        // A(1)
  DMAB(1);           // B(1)
  BODY(2, 0, 1, 0, rA0, rA1);   // tt=0

  for (int it = 0; it < 4; ++it) {  // tt = 1..24
    BODY(0, 1, 0, 1, rA1, rA0);     // tt%6=1
    BODY(1, 2, 1, 0, rA0, rA1);     // 2
    BODY(2, 0, 0, 1, rA1, rA0);     // 3
    BODY(0, 1, 1, 0, rA0, rA1);     // 4
    BODY(1, 2, 0, 1, rA1, rA0);     // 5
    BODY(2, 0, 1, 0, rA0, rA1);     // 0
  }
  BODY(0, 1, 0, 1, rA1, rA0);  // tt=25
  BODY(1, 2, 1, 0, rA0, rA1);  // 26
  BODY(2, 0, 0, 1, rA1, rA0);  // 27
  BODY(0, 1, 1, 0, rA0, rA1);  // 28
  BODY(1, 2, 0, 1, rA1, rA0);  // 29  (loads A(31) -> rA1, writes A(30) -> buf0)
  // tail: write A(31) (held in rA1!) into buf1, drain everything
  WRITEA(rA1, 1);
  K2WAIT(0);
  K2BAR();
  COMPUTE(0, 0);   // step 30: B 30%3=0, A 30&1=0
  K2BAR();
  COMPUTE(1, 1);   // step 31: B 31%3=1, A 31&1=1

  // epilogue: f16 partial store (C/D: col=lane&31 -> j, row=(r&3)+8*(r>>2)+4*oct -> e)
#pragma unroll
  for (int f = 0; f < 5; ++f) {
    int jg = wj * 160 + f * 32 + l31;
    int ebase = e0 + we * 32 + 4 * oct;
#pragma unroll
    for (int r = 0; r < 16; ++r) {
      int eg = ebase + (r & 3) + 8 * (r >> 2);
      Zout[(size_t)eg * DP + jg] = (f16)acc[f][r];
    }
  }
#undef LOADA
#undef DMAB
#undef WRITEA
#undef COMPUTE
#undef BODY
}

// ---------------------------------------------------------------- k2s: sum 16 f16 partials -> EF0 (f16), full-BW grid
__global__ __launch_bounds__(256) void k2s_sum(const f16* __restrict__ Zp,
                                               f16* __restrict__ EF0) {
  const size_t idx = ((size_t)blockIdx.x * 256 + threadIdx.x) * 8;
  float s[8];
#pragma unroll
  for (int z = 0; z < 8; ++z) s[z] = 0.f;
#pragma unroll
  for (int p = 0; p < 16; ++p) {
    f16x8 v = *(const f16x8*)(Zp + (size_t)p * PS + idx);
#pragma unroll
    for (int z = 0; z < 8; ++z) s[z] += (float)v[z];
  }
  f16x8 o;
#pragma unroll
  for (int z = 0; z < 8; ++z) o[z] = (f16)s[z];
  *(f16x8*)(EF0 + idx) = o;
}

// ---------------------------------------------------------------- k2b: att = EF0 @ W_att (f32 out), 64 blocks x 64e
// LDS: Bbuf[2] @ 0/20480 (320 rows x 64B); Abuf[2] @ 40960/45056 (64 rows x 64B)
__global__ __launch_bounds__(256, 1) void k2b_att(const f16* __restrict__ EF0,
                                                  const f16* __restrict__ WT,
                                                  float* __restrict__ att) {
  __shared__ __align__(16) char lds[49152];
  const int t = threadIdx.x, lane = t & 63, wid = t >> 6;
  const int e0 = blockIdx.x * 64;
  const int we = wid >> 1, wj = wid & 1;
  const int l31 = lane & 31, oct = lane >> 5;
  int sl[2];
#pragma unroll
  for (int kk = 0; kk < 2; ++kk)
    sl[kk] = (((kk * 2 + oct) ^ ((l31 >> 1) & 3)) & 3) << 4;
  const int arow = (we * 32 + l31) * 64;
  const int brow = (wj * 160 + l31) * 64;
  const int srcsw = 8 * ((lane & 3) ^ ((lane >> 3) & 3));
  const f16* pA = EF0 + (size_t)(e0 + wid * 16 + (lane >> 2)) * DP + srcsw;
  const f16* pB = WT + (size_t)(wid * 80 + (lane >> 2)) * DP + srcsw;

  f32x16 acc[5];
#pragma unroll
  for (int f = 0; f < 5; ++f)
#pragma unroll
    for (int r = 0; r < 16; ++r) acc[f][r] = 0.f;

#define STAGE2(S)                                                              \
  {                                                                            \
    GLOAD_LDS16(pA, lds + 40960 + (S)*4096 + wid * 1024);                      \
    pA += 32;                                                                  \
    _Pragma("unroll") for (int i = 0; i < 5; ++i) {                            \
      GLOAD_LDS16(pB + (size_t)(i * 16) * DP,                                  \
                  lds + (S)*20480 + wid * 5120 + i * 1024);                    \
    }                                                                          \
    pB += 32;                                                                  \
  }
#define COMPUTE2(S)                                                            \
  {                                                                            \
    _Pragma("unroll") for (int kk = 0; kk < 2; ++kk) {                         \
      f16x8 a_ = *(const f16x8*)(lds + 40960 + (S)*4096 + arow + sl[kk]);      \
      _Pragma("unroll") for (int f = 0; f < 5; ++f) {                          \
        f16x8 b_ = *(const f16x8*)(lds + (S)*20480 + brow + f * 2048 + sl[kk]); \
        acc[f] = __builtin_amdgcn_mfma_f32_32x32x16_f16(a_, b_, acc[f], 0, 0, 0); \
      }                                                                        \
    }                                                                          \
  }

  STAGE2(0);
  STAGE2(1);
  K2WAIT(6);
  K2BAR();
  for (int tt = 0; tt < 8; ++tt) {
    COMPUTE2(tt & 1);
    K2BAR();
    STAGE2(tt & 1);
    K2WAIT(6);
    K2BAR();
  }
  COMPUTE2(0);
  K2BAR();
  K2WAIT(0);
  COMPUTE2(1);

#pragma unroll
  for (int f = 0; f < 5; ++f) {
    int jg = wj * 160 + f * 32 + l31;
    int ebase = e0 + we * 32 + 4 * oct;
#pragma unroll
    for (int r = 0; r < 16; ++r) {
      int eg = ebase + (r & 3) + 8 * (r >> 2);
      att[(size_t)eg * DP + jg] = acc[f][r];
    }
  }
#undef STAGE2
#undef COMPUTE2
}

// ---------------------------------------------------------------- k3: softmax(att) weights EF0 + projection
__global__ __launch_bounds__(256) void k3_edge(const float* __restrict__ att,
                                               const f16* __restrict__ EF0,
                                               const float* __restrict__ edge_feats,
                                               const float* __restrict__ Wproj,
                                               const float* __restrict__ alphaP,
                                               const float* __restrict__ ecWatt,
                                               float* __restrict__ ef,
                                               float* __restrict__ scores) {
  __shared__ float efw[16][304];
  const int t = threadIdx.x, lane = t & 63, w = t >> 6;
  const int e0 = blockIdx.x * 16;
  for (int el = 0; el < 4; ++el) {
    int e = e0 + w * 4 + el;
    const size_t ro = (size_t)e * DP;
    float p[5];
    float mx = -1e30f;
#pragma unroll
    for (int u = 0; u < 5; ++u) {
      int d = u * 64 + lane;
      p[u] = (d < ND) ? att[ro + d] : -1e30f;
      mx = fmaxf(mx, p[u]);
    }
    for (int o = 32; o; o >>= 1) mx = fmaxf(mx, __shfl_xor(mx, o));
    float s = 0.f;
#pragma unroll
    for (int u = 0; u < 5; ++u) {
      int d = u * 64 + lane;
      float pe = (d < ND) ? expf(p[u] - mx) : 0.f;
      p[u] = pe;
      s += pe;
    }
    for (int o = 32; o; o >>= 1) s += __shfl_xor(s, o);
    float inv = 1.f / s;
#pragma unroll
    for (int u = 0; u < 5; ++u) {
      int d = u * 64 + lane;
      if (d < 304)
        efw[w * 4 + el][d] = (d < ND) ? (float)EF0[ro + d] * p[u] * inv : 0.f;
    }
  }
  __syncthreads();
  const int jl = lane & 15, kc = lane >> 4;
  const float alpha = alphaP[0];
  float acc[4][19];
#pragma unroll
  for (int ei = 0; ei < 4; ++ei)
#pragma unroll
    for (int jj = 0; jj < 19; ++jj) acc[ei][jj] = 0.f;
  const int d0 = kc * 75;
  const float* efw0 = &efw[w * 4 + 0][0];
  const float* efw1 = &efw[w * 4 + 1][0];
  const float* efw2 = &efw[w * 4 + 2][0];
  const float* efw3 = &efw[w * 4 + 3][0];
  for (int dd = 0; dd < 75; ++dd) {
    int d = d0 + dd;
    const float* wr = Wproj + (size_t)d * ND + jl;
    float w0 = efw0[d], w1 = efw1[d], w2 = efw2[d], w3 = efw3[d];
#pragma unroll
    for (int jj = 0; jj < 19; ++jj) {
      int j = jl + jj * 16;
      float wv = (j < ND) ? wr[jj * 16] : 0.f;
      acc[0][jj] += w0 * wv;
      acc[1][jj] += w1 * wv;
      acc[2][jj] += w2 * wv;
      acc[3][jj] += w3 * wv;
    }
  }
#pragma unroll
  for (int ei = 0; ei < 4; ++ei)
#pragma unroll
    for (int jj = 0; jj < 19; ++jj) {
      acc[ei][jj] += __shfl_xor(acc[ei][jj], 16);
      acc[ei][jj] += __shfl_xor(acc[ei][jj], 32);
    }
  float scp[4] = {0.f, 0.f, 0.f, 0.f};
#pragma unroll
  for (int ei = 0; ei < 4; ++ei) {
    int e = e0 + w * 4 + ei;
#pragma unroll
    for (int jj = 0; jj < 19; ++jj) {
      int j = jl + jj * 16;
      float v = 0.f;
      if (j < ND) {
        v = alpha * edge_feats[(size_t)e * ND + j] + (1.f - alpha) * acc[ei][jj];
        scp[ei] += v * ecWatt[j];
      }
      if (kc == 0) ef[(size_t)e * 304 + j] = v;
    }
  }
#pragma unroll
  for (int ei = 0; ei < 4; ++ei)
    for (int o = 8; o; o >>= 1) scp[ei] += __shfl_xor(scp[ei], o);
  if (lane == 0) {
#pragma unroll
    for (int ei = 0; ei < 4; ++ei) scores[e0 + w * 4 + ei] = scp[ei];
  }
}

// ---------------------------------------------------------------- k4ab: per-block softmax recompute + weighted pooling
__global__ __launch_bounds__(256) void k4ab_pool(const float* __restrict__ sc,
                                                 const float* __restrict__ ef,
                                                 float* __restrict__ pp) {
  __shared__ float redm[4];
  __shared__ float reds[4];
  __shared__ float wsh[64];
  const int t = threadIdx.x, lane = t & 63, w = t >> 6;
  float v[16];
  float mx = -1e30f;
#pragma unroll
  for (int u = 0; u < 16; ++u) {
    v[u] = sc[t + u * 256];
    mx = fmaxf(mx, v[u]);
  }
  for (int o = 32; o; o >>= 1) mx = fmaxf(mx, __shfl_xor(mx, o));
  if (lane == 0) redm[w] = mx;
  __syncthreads();
  float m2 = fmaxf(fmaxf(redm[0], redm[1]), fmaxf(redm[2], redm[3]));
  float s = 0.f;
#pragma unroll
  for (int u = 0; u < 16; ++u) s += expf(v[u] - m2);
  for (int o = 32; o; o >>= 1) s += __shfl_xor(s, o);
  if (lane == 0) reds[w] = s;
  __syncthreads();
  float inv = 1.f / (reds[0] + reds[1] + reds[2] + reds[3]);
  const int e0 = blockIdx.x * 64;
  if (t < 64) wsh[t] = expf(sc[e0 + t] - m2) * inv;
  __syncthreads();
  for (int j = t; j < 304; j += 256) {
    float acc = 0.f;
#pragma unroll 8
    for (int e = 0; e < 64; ++e) acc += wsh[e] * ef[(size_t)(e0 + e) * 304 + j];
    pp[blockIdx.x * 304 + j] = acc;
  }
}

// ---------------------------------------------------------------- k4c: final reduce + two matvecs -> 3 logits
__global__ __launch_bounds__(320) void k4c_final(const float* __restrict__ pp,
                                                 const float* __restrict__ ecWp,
                                                 const float* __restrict__ ecb,
                                                 const float* __restrict__ fcW,
                                                 const float* __restrict__ fcb,
                                                 float* __restrict__ out) {
  __shared__ float pooled[304];
  __shared__ float o[304];
  const int t = threadIdx.x;
  if (t < 304) {
    float acc = 0.f;
#pragma unroll 8
    for (int b = 0; b < 64; ++b) acc += pp[b * 304 + t];
    pooled[t] = acc;
  }
  __syncthreads();
  if (t < ND) {
    float acc = ecb[t];
#pragma unroll 4
    for (int j = 0; j < ND; ++j) acc += pooled[j] * ecWp[(size_t)j * ND + t];
    o[t] = acc;
  }
  __syncthreads();
  if (t < 64) {
#pragma unroll
    for (int c = 0; c < 3; ++c) {
      float a = 0.f;
      for (int j2 = t; j2 < ND; j2 += 64) a += o[j2] * fcW[j2 * 3 + c];
      for (int off = 32; off; off >>= 1) a += __shfl_xor(a, off);
      if (t == 0) out[c] = a + fcb[c];
    }
  }
}

// ----------------------------------------------------------------
extern "C" void kernel_launch(void* const* d_in, const int* in_sizes, int n_in,
                              void* d_out, int out_size, void* d_ws, size_t ws_size,
                              hipStream_t stream) {
  const float* X = (const float*)d_in[0];
  const float* EFEATS = (const float*)d_in[1];
  const float* INC = (const float*)d_in[2];
  const float* WATT = (const float*)d_in[3];
  const float* WPROJ = (const float*)d_in[4];
  const float* ALPHA = (const float*)d_in[5];
  const float* ECATT = (const float*)d_in[6];
  const float* ECWP = (const float*)d_in[7];
  const float* ECB = (const float*)d_in[8];
  const float* FCW = (const float*)d_in[9];
  const float* FCB = (const float*)d_in[10];

  char* ws = (char*)d_ws;
  f16* XT = (f16*)(ws);                    // [0, 10485760)
  f16* Zp = (f16*)(ws + 10485760);         // 16 x 2621440 B -> [10485760, 52428800)
  f16* WT = (f16*)(ws + 52428800);         // [52428800, 52633600)
  f16* EF0 = (f16*)(ws + 52633600);        // [52633600, 55255040)
  float* att = (float*)(ws + 55255040);    // [55255040, 60497920)
  float* ef = (float*)(ws + 60497920);     // [60497920, 65478656)
  float* sc = (float*)(ws + 65478656);     // 4096*4
  float* pp = (float*)(ws + 65495040);     // 64*304*4

  hipLaunchKernelGGL(k01_prep, dim3(656), dim3(256), 0, stream, X, WATT, XT, WT);
  hipLaunchKernelGGL(k2_bigmm, dim3(512), dim3(512), 0, stream, INC, XT, Zp);
  hipLaunchKernelGGL(k2s_sum, dim3(640), dim3(256), 0, stream, Zp, EF0);
  hipLaunchKernelGGL(k2b_att, dim3(64), dim3(256), 0, stream, EF0, WT, att);
  hipLaunchKernelGGL(k3_edge, dim3(256), dim3(256), 0, stream, att, EF0, EFEATS,
                     WPROJ, ALPHA, ECATT, ef, sc);
  hipLaunchKernelGGL(k4ab_pool, dim3(64), dim3(256), 0, stream, sc, ef, pp);
  hipLaunchKernelGGL(k4c_final, dim3(1), dim3(320), 0, stream, pp, ECWP, ECB, FCW,
                     FCB, (float*)d_out);
}

// Round 14
// 261.870 us; speedup vs baseline: 1.0016x; 1.0016x over previous
//
#include <hip/hip_runtime.h>
#include <math.h>

typedef _Float16 f16;
typedef _Float16 f16x8 __attribute__((ext_vector_type(8)));
typedef _Float16 f16x4 __attribute__((ext_vector_type(4)));
typedef __fp16 fp16x2 __attribute__((ext_vector_type(2)));
typedef float f32x4 __attribute__((ext_vector_type(4)));
typedef float f32x16 __attribute__((ext_vector_type(16)));

#define NM 16384    // nodes (K of big GEMM)
#define NE 4096     // hyperedges
#define ND 300      // feature dim
#define DP 320      // padded feature dim
#define PS 1310720  // per-partial f16 elements (4096*320)

#define GLOAD_LDS16(gsrc, ldst)                                              \
  __builtin_amdgcn_global_load_lds(                                          \
      (__attribute__((address_space(1))) void*)(gsrc),                       \
      (__attribute__((address_space(3))) void*)(ldst), 16, 0, 0)

#define K2WAIT(N) asm volatile("s_waitcnt vmcnt(" #N ") lgkmcnt(0)" ::: "memory")
#define K2BAR()                                        \
  do {                                                 \
    asm volatile("" ::: "memory");                     \
    __builtin_amdgcn_s_barrier();                      \
    asm volatile("" ::: "memory");                     \
  } while (0)
#define K2BARW()                                       \
  do {                                                 \
    asm volatile("s_waitcnt lgkmcnt(0)" ::: "memory"); \
    __builtin_amdgcn_s_barrier();                      \
    asm volatile("" ::: "memory");                     \
  } while (0)

// ---------------------------------------------------------------- k01: X -> XT (f16, padded) + W_att^T -> f16
__global__ __launch_bounds__(256) void k01_prep(const float* __restrict__ X,
                                                const float* __restrict__ Watt,
                                                f16* __restrict__ XT,
                                                f16* __restrict__ WT) {
  __shared__ f16 tile[64][324];
  const int bx = blockIdx.x;
  if (bx < 256) {
    int m0 = bx * 64;
    for (int idx = threadIdx.x; idx < 64 * 80; idx += 256) {
      int m = idx / 80, q = idx % 80;
      int d = q * 4;
      float4 v = make_float4(0.f, 0.f, 0.f, 0.f);
      if (d < ND) v = *(const float4*)(X + (size_t)(m0 + m) * ND + d);
      tile[m][d] = (f16)v.x; tile[m][d + 1] = (f16)v.y;
      tile[m][d + 2] = (f16)v.z; tile[m][d + 3] = (f16)v.w;
    }
    __syncthreads();
    for (int idx = threadIdx.x; idx < DP * 8; idx += 256) {
      int d = idx >> 3, part = idx & 7;
      f16x8 hv;
#pragma unroll
      for (int i = 0; i < 8; ++i) hv[i] = tile[part * 8 + i][d];
      *(f16x8*)(XT + (size_t)d * NM + m0 + part * 8) = hv;
    }
  } else {
    int idx = (bx - 256) * 256 + threadIdx.x;
    if (idx < DP * DP) {
      int j = idx / DP, d = idx % DP;
      float v = (j < ND && d < ND) ? Watt[d * ND + j] : 0.f;
      WT[(size_t)j * DP + d] = (f16)v;
    }
  }
}

// ---------------------------------------------------------------- k2 v13: EF0 = inc^T @ X, 32x32x16 MFMA
// block 128e x 320j x BK32, 512 thr / 8 waves (4we x 2wj), wave 32e x 160j.
// v13: launch_bounds(512, 1) — v12's (512,2) forced a 128-reg/wave cap
// (4 waves/SIMD) with acc[5]=80 AGPR -> accumulator spill in the K-loop.
// (512,1) = 1 block/CU, 2 waves/SIMD, 256-reg budget, no spill.
// grid 512 = 32 eb x 16 kb, xcd = kb&7. B-ring-3 + A-ring-2, implicit vmcnt.
// LDS: B @ 0/20480/40960 (320 rows x 64B); A @ 61440/69632 (128 rows x 64B)
__global__ __launch_bounds__(512, 1) void k2_bigmm(const float* __restrict__ inc,
                                                   const f16* __restrict__ XT,
                                                   f16* __restrict__ Zp) {
  __shared__ __align__(16) char lds[77824];
  const int t = threadIdx.x, lane = t & 63, wid = t >> 6;
  const int bx = blockIdx.x;
  const int kb = (bx & 7) | (((bx >> 3) & 1) << 3);
  const int eb = bx >> 4;
  const int e0 = eb * 128;
  const size_t kbase = (size_t)kb * 1024;
  f16* __restrict__ Zout = Zp + (size_t)kb * PS;

  const int we = wid >> 1, wj = wid & 1;
  const int l31 = lane & 31, oct = lane >> 5;
  int sl[2];
#pragma unroll
  for (int kk = 0; kk < 2; ++kk)
    sl[kk] = (((kk * 2 + oct) ^ ((l31 >> 1) & 3)) & 3) << 4;
  const int arow = (we * 32 + l31) * 64;
  const int brow = (wj * 160 + l31) * 64;
  // A staging: thread = (ae = t&127, kq = t>>7); 8 scalar k-loads, 1 uint4 write
  const int ae = t & 127, kq = t >> 7;
  const int wa = 61440 + ae * 64 + (((kq ^ ((ae >> 1) & 3)) & 3) << 4);
  const float* pA = inc + (kbase + kq * 8) * NE + e0 + ae;
  // B staging: 20 units of 16 rows; wave w -> units {w, 8+w, 16+w if w<4}
  const int bsw = 8 * ((lane & 3) ^ ((lane >> 3) & 3));
  const f16* pB0 = XT + (size_t)(wid * 16 + (lane >> 2)) * NM + kbase + bsw;
  const f16* pB1 = XT + (size_t)((8 + wid) * 16 + (lane >> 2)) * NM + kbase + bsw;
  const f16* pB2 = XT + (size_t)((16 + wid) * 16 + (lane >> 2)) * NM + kbase + bsw;

  float rA0[8], rA1[8];
  f32x16 acc[5];
#pragma unroll
  for (int f = 0; f < 5; ++f)
#pragma unroll
    for (int r = 0; r < 16; ++r) acc[f][r] = 0.f;

#define LOADA(R)                                                               \
  {                                                                            \
    _Pragma("unroll") for (int i = 0; i < 8; ++i)                              \
        R[i] = pA[(size_t)i * NE];                                             \
    pA += (size_t)32 * NE;                                                     \
  }
#define DMAB(S)                                                                \
  {                                                                            \
    GLOAD_LDS16(pB0, lds + (S)*20480 + wid * 1024);                            \
    GLOAD_LDS16(pB1, lds + (S)*20480 + (8 + wid) * 1024);                      \
    if (wid < 4) GLOAD_LDS16(pB2, lds + (S)*20480 + (16 + wid) * 1024);        \
    pB0 += 32; pB1 += 32; pB2 += 32;                                           \
  }
#define WRITEA(R, S)                                                           \
  {                                                                            \
    union { fp16x2 h; uint32_t u; } u_[4];                                     \
    _Pragma("unroll") for (int z = 0; z < 4; ++z)                              \
      u_[z].h = __builtin_amdgcn_cvt_pkrtz(R[2 * z], R[2 * z + 1]);            \
    *(uint4*)(lds + wa + (S)*8192) = make_uint4(u_[0].u, u_[1].u, u_[2].u, u_[3].u); \
  }
#define COMPUTE(BS, AS)                                                        \
  {                                                                            \
    __builtin_amdgcn_s_setprio(1);                                             \
    _Pragma("unroll") for (int kk = 0; kk < 2; ++kk) {                         \
      f16x8 a_ = *(const f16x8*)(lds + 61440 + (AS)*8192 + arow + sl[kk]);     \
      _Pragma("unroll") for (int f = 0; f < 5; ++f) {                          \
        f16x8 b_ = *(const f16x8*)(lds + (BS)*20480 + brow + f * 2048 + sl[kk]); \
        acc[f] = __builtin_amdgcn_mfma_f32_32x32x16_f16(a_, b_, acc[f], 0, 0, 0); \
      }                                                                        \
    }                                                                          \
    __builtin_amdgcn_s_setprio(0);                                             \
  }
// BODY(tt): stage B(tt+2), load A(tt+2), write A(tt+1); barrier; compute tt.
#define BODY(BSTG, BCMP, AW, AC, RL, RW)                                       \
  DMAB(BSTG);                                                                  \
  LOADA(RL);                                                                   \
  WRITEA(RW, AW); /* implicit vmcnt drains A(tt+1) => B(tt+1),B(tt) resident */\
  K2BARW();                                                                    \
  COMPUTE(BCMP, AC);                                                           \
  K2BAR();

  // prologue
  LOADA(rA0);        // A(0)
  DMAB(0);           // B(0)
  WRITEA(rA0, 0);    // A(0) -> Abuf0 (implicit wait A(0))
  LOADA(rA1);        // A(1)
  DMAB(1);           // B(1)
  BODY(2, 0, 1, 0, rA0, rA1);   // tt=0

  for (int it = 0; it < 4; ++it) {  // tt = 1..24
    BODY(0, 1, 0, 1, rA1, rA0);     // tt%6=1
    BODY(1, 2, 1, 0, rA0, rA1);     // 2
    BODY(2, 0, 0, 1, rA1, rA0);     // 3
    BODY(0, 1, 1, 0, rA0, rA1);     // 4
    BODY(1, 2, 0, 1, rA1, rA0);     // 5
    BODY(2, 0, 1, 0, rA0, rA1);     // 0
  }
  BODY(0, 1, 0, 1, rA1, rA0);  // tt=25
  BODY(1, 2, 1, 0, rA0, rA1);  // 26
  BODY(2, 0, 0, 1, rA1, rA0);  // 27
  BODY(0, 1, 1, 0, rA0, rA1);  // 28
  BODY(1, 2, 0, 1, rA1, rA0);  // 29  (loads A(31) -> rA1, writes A(30) -> buf0)
  // tail: write A(31) (held in rA1), drain everything
  WRITEA(rA1, 1);
  K2WAIT(0);
  K2BAR();
  COMPUTE(0, 0);   // step 30: B 30%3=0, A 30&1=0
  K2BAR();
  COMPUTE(1, 1);   // step 31: B 31%3=1, A 31&1=1

  // epilogue: f16 partial store (C/D: col=lane&31 -> j, row=(r&3)+8*(r>>2)+4*oct -> e)
#pragma unroll
  for (int f = 0; f < 5; ++f) {
    int jg = wj * 160 + f * 32 + l31;
    int ebase = e0 + we * 32 + 4 * oct;
#pragma unroll
    for (int r = 0; r < 16; ++r) {
      int eg = ebase + (r & 3) + 8 * (r >> 2);
      Zout[(size_t)eg * DP + jg] = (f16)acc[f][r];
    }
  }
#undef LOADA
#undef DMAB
#undef WRITEA
#undef COMPUTE
#undef BODY
}

// ---------------------------------------------------------------- k2s: sum 16 f16 partials -> EF0 (f16), full-BW grid
__global__ __launch_bounds__(256) void k2s_sum(const f16* __restrict__ Zp,
                                               f16* __restrict__ EF0) {
  const size_t idx = ((size_t)blockIdx.x * 256 + threadIdx.x) * 8;
  float s[8];
#pragma unroll
  for (int z = 0; z < 8; ++z) s[z] = 0.f;
#pragma unroll
  for (int p = 0; p < 16; ++p) {
    f16x8 v = *(const f16x8*)(Zp + (size_t)p * PS + idx);
#pragma unroll
    for (int z = 0; z < 8; ++z) s[z] += (float)v[z];
  }
  f16x8 o;
#pragma unroll
  for (int z = 0; z < 8; ++z) o[z] = (f16)s[z];
  *(f16x8*)(EF0 + idx) = o;
}

// ---------------------------------------------------------------- k2b: att = EF0 @ W_att (f32 out), 64 blocks x 64e
// LDS: Bbuf[2] @ 0/20480 (320 rows x 64B); Abuf[2] @ 40960/45056 (64 rows x 64B)
__global__ __launch_bounds__(256, 1) void k2b_att(const f16* __restrict__ EF0,
                                                  const f16* __restrict__ WT,
                                                  float* __restrict__ att) {
  __shared__ __align__(16) char lds[49152];
  const int t = threadIdx.x, lane = t & 63, wid = t >> 6;
  const int e0 = blockIdx.x * 64;
  const int we = wid >> 1, wj = wid & 1;
  const int l31 = lane & 31, oct = lane >> 5;
  int sl[2];
#pragma unroll
  for (int kk = 0; kk < 2; ++kk)
    sl[kk] = (((kk * 2 + oct) ^ ((l31 >> 1) & 3)) & 3) << 4;
  const int arow = (we * 32 + l31) * 64;
  const int brow = (wj * 160 + l31) * 64;
  const int srcsw = 8 * ((lane & 3) ^ ((lane >> 3) & 3));
  const f16* pA = EF0 + (size_t)(e0 + wid * 16 + (lane >> 2)) * DP + srcsw;
  const f16* pB = WT + (size_t)(wid * 80 + (lane >> 2)) * DP + srcsw;

  f32x16 acc[5];
#pragma unroll
  for (int f = 0; f < 5; ++f)
#pragma unroll
    for (int r = 0; r < 16; ++r) acc[f][r] = 0.f;

#define STAGE2(S)                                                              \
  {                                                                            \
    GLOAD_LDS16(pA, lds + 40960 + (S)*4096 + wid * 1024);                      \
    pA += 32;                                                                  \
    _Pragma("unroll") for (int i = 0; i < 5; ++i) {                            \
      GLOAD_LDS16(pB + (size_t)(i * 16) * DP,                                  \
                  lds + (S)*20480 + wid * 5120 + i * 1024);                    \
    }                                                                          \
    pB += 32;                                                                  \
  }
#define COMPUTE2(S)                                                            \
  {                                                                            \
    _Pragma("unroll") for (int kk = 0; kk < 2; ++kk) {                         \
      f16x8 a_ = *(const f16x8*)(lds + 40960 + (S)*4096 + arow + sl[kk]);      \
      _Pragma("unroll") for (int f = 0; f < 5; ++f) {                          \
        f16x8 b_ = *(const f16x8*)(lds + (S)*20480 + brow + f * 2048 + sl[kk]); \
        acc[f] = __builtin_amdgcn_mfma_f32_32x32x16_f16(a_, b_, acc[f], 0, 0, 0); \
      }                                                                        \
    }                                                                          \
  }

  STAGE2(0);
  STAGE2(1);
  K2WAIT(6);
  K2BAR();
  for (int tt = 0; tt < 8; ++tt) {
    COMPUTE2(tt & 1);
    K2BAR();
    STAGE2(tt & 1);
    K2WAIT(6);
    K2BAR();
  }
  COMPUTE2(0);
  K2BAR();
  K2WAIT(0);
  COMPUTE2(1);

#pragma unroll
  for (int f = 0; f < 5; ++f) {
    int jg = wj * 160 + f * 32 + l31;
    int ebase = e0 + we * 32 + 4 * oct;
#pragma unroll
    for (int r = 0; r < 16; ++r) {
      int eg = ebase + (r & 3) + 8 * (r >> 2);
      att[(size_t)eg * DP + jg] = acc[f][r];
    }
  }
#undef STAGE2
#undef COMPUTE2
}

// ---------------------------------------------------------------- k3: softmax(att) weights EF0 + projection
__global__ __launch_bounds__(256) void k3_edge(const float* __restrict__ att,
                                               const f16* __restrict__ EF0,
                                               const float* __restrict__ edge_feats,
                                               const float* __restrict__ Wproj,
                                               const float* __restrict__ alphaP,
                                               const float* __restrict__ ecWatt,
                                               float* __restrict__ ef,
                                               float* __restrict__ scores) {
  __shared__ float efw[16][304];
  const int t = threadIdx.x, lane = t & 63, w = t >> 6;
  const int e0 = blockIdx.x * 16;
  for (int el = 0; el < 4; ++el) {
    int e = e0 + w * 4 + el;
    const size_t ro = (size_t)e * DP;
    float p[5];
    float mx = -1e30f;
#pragma unroll
    for (int u = 0; u < 5; ++u) {
      int d = u * 64 + lane;
      p[u] = (d < ND) ? att[ro + d] : -1e30f;
      mx = fmaxf(mx, p[u]);
    }
    for (int o = 32; o; o >>= 1) mx = fmaxf(mx, __shfl_xor(mx, o));
    float s = 0.f;
#pragma unroll
    for (int u = 0; u < 5; ++u) {
      int d = u * 64 + lane;
      float pe = (d < ND) ? expf(p[u] - mx) : 0.f;
      p[u] = pe;
      s += pe;
    }
    for (int o = 32; o; o >>= 1) s += __shfl_xor(s, o);
    float inv = 1.f / s;
#pragma unroll
    for (int u = 0; u < 5; ++u) {
      int d = u * 64 + lane;
      if (d < 304)
        efw[w * 4 + el][d] = (d < ND) ? (float)EF0[ro + d] * p[u] * inv : 0.f;
    }
  }
  __syncthreads();
  const int jl = lane & 15, kc = lane >> 4;
  const float alpha = alphaP[0];
  float acc[4][19];
#pragma unroll
  for (int ei = 0; ei < 4; ++ei)
#pragma unroll
    for (int jj = 0; jj < 19; ++jj) acc[ei][jj] = 0.f;
  const int d0 = kc * 75;
  const float* efw0 = &efw[w * 4 + 0][0];
  const float* efw1 = &efw[w * 4 + 1][0];
  const float* efw2 = &efw[w * 4 + 2][0];
  const float* efw3 = &efw[w * 4 + 3][0];
  for (int dd = 0; dd < 75; ++dd) {
    int d = d0 + dd;
    const float* wr = Wproj + (size_t)d * ND + jl;
    float w0 = efw0[d], w1 = efw1[d], w2 = efw2[d], w3 = efw3[d];
#pragma unroll
    for (int jj = 0; jj < 19; ++jj) {
      int j = jl + jj * 16;
      float wv = (j < ND) ? wr[jj * 16] : 0.f;
      acc[0][jj] += w0 * wv;
      acc[1][jj] += w1 * wv;
      acc[2][jj] += w2 * wv;
      acc[3][jj] += w3 * wv;
    }
  }
#pragma unroll
  for (int ei = 0; ei < 4; ++ei)
#pragma unroll
    for (int jj = 0; jj < 19; ++jj) {
      acc[ei][jj] += __shfl_xor(acc[ei][jj], 16);
      acc[ei][jj] += __shfl_xor(acc[ei][jj], 32);
    }
  float scp[4] = {0.f, 0.f, 0.f, 0.f};
#pragma unroll
  for (int ei = 0; ei < 4; ++ei) {
    int e = e0 + w * 4 + ei;
#pragma unroll
    for (int jj = 0; jj < 19; ++jj) {
      int j = jl + jj * 16;
      float v = 0.f;
      if (j < ND) {
        v = alpha * edge_feats[(size_t)e * ND + j] + (1.f - alpha) * acc[ei][jj];
        scp[ei] += v * ecWatt[j];
      }
      if (kc == 0) ef[(size_t)e * 304 + j] = v;
    }
  }
#pragma unroll
  for (int ei = 0; ei < 4; ++ei)
    for (int o = 8; o; o >>= 1) scp[ei] += __shfl_xor(scp[ei], o);
  if (lane == 0) {
#pragma unroll
    for (int ei = 0; ei < 4; ++ei) scores[e0 + w * 4 + ei] = scp[ei];
  }
}

// ---------------------------------------------------------------- k4ab: per-block softmax recompute + weighted pooling
__global__ __launch_bounds__(256) void k4ab_pool(const float* __restrict__ sc,
                                                 const float* __restrict__ ef,
                                                 float* __restrict__ pp) {
  __shared__ float redm[4];
  __shared__ float reds[4];
  __shared__ float wsh[64];
  const int t = threadIdx.x, lane = t & 63, w = t >> 6;
  float v[16];
  float mx = -1e30f;
#pragma unroll
  for (int u = 0; u < 16; ++u) {
    v[u] = sc[t + u * 256];
    mx = fmaxf(mx, v[u]);
  }
  for (int o = 32; o; o >>= 1) mx = fmaxf(mx, __shfl_xor(mx, o));
  if (lane == 0) redm[w] = mx;
  __syncthreads();
  float m2 = fmaxf(fmaxf(redm[0], redm[1]), fmaxf(redm[2], redm[3]));
  float s = 0.f;
#pragma unroll
  for (int u = 0; u < 16; ++u) s += expf(v[u] - m2);
  for (int o = 32; o; o >>= 1) s += __shfl_xor(s, o);
  if (lane == 0) reds[w] = s;
  __syncthreads();
  float inv = 1.f / (reds[0] + reds[1] + reds[2] + reds[3]);
  const int e0 = blockIdx.x * 64;
  if (t < 64) wsh[t] = expf(sc[e0 + t] - m2) * inv;
  __syncthreads();
  for (int j = t; j < 304; j += 256) {
    float acc = 0.f;
#pragma unroll 8
    for (int e = 0; e < 64; ++e) acc += wsh[e] * ef[(size_t)(e0 + e) * 304 + j];
    pp[blockIdx.x * 304 + j] = acc;
  }
}

// ---------------------------------------------------------------- k4c: final reduce + two matvecs -> 3 logits
__global__ __launch_bounds__(320) void k4c_final(const float* __restrict__ pp,
                                                 const float* __restrict__ ecWp,
                                                 const float* __restrict__ ecb,
                                                 const float* __restrict__ fcW,
                                                 const float* __restrict__ fcb,
                                                 float* __restrict__ out) {
  __shared__ float pooled[304];
  __shared__ float o[304];
  const int t = threadIdx.x;
  if (t < 304) {
    float acc = 0.f;
#pragma unroll 8
    for (int b = 0; b < 64; ++b) acc += pp[b * 304 + t];
    pooled[t] = acc;
  }
  __syncthreads();
  if (t < ND) {
    float acc = ecb[t];
#pragma unroll 4
    for (int j = 0; j < ND; ++j) acc += pooled[j] * ecWp[(size_t)j * ND + t];
    o[t] = acc;
  }
  __syncthreads();
  if (t < 64) {
#pragma unroll
    for (int c = 0; c < 3; ++c) {
      float a = 0.f;
      for (int j2 = t; j2 < ND; j2 += 64) a += o[j2] * fcW[j2 * 3 + c];
      for (int off = 32; off; off >>= 1) a += __shfl_xor(a, off);
      if (t == 0) out[c] = a + fcb[c];
    }
  }
}

// ----------------------------------------------------------------
extern "C" void kernel_launch(void* const* d_in, const int* in_sizes, int n_in,
                              void* d_out, int out_size, void* d_ws, size_t ws_size,
                              hipStream_t stream) {
  const float* X = (const float*)d_in[0];
  const float* EFEATS = (const float*)d_in[1];
  const float* INC = (const float*)d_in[2];
  const float* WATT = (const float*)d_in[3];
  const float* WPROJ = (const float*)d_in[4];
  const float* ALPHA = (const float*)d_in[5];
  const float* ECATT = (const float*)d_in[6];
  const float* ECWP = (const float*)d_in[7];
  const float* ECB = (const float*)d_in[8];
  const float* FCW = (const float*)d_in[9];
  const float* FCB = (const float*)d_in[10];

  char* ws = (char*)d_ws;
  f16* XT = (f16*)(ws);                    // [0, 10485760)
  f16* Zp = (f16*)(ws + 10485760);         // 16 x 2621440 B -> [10485760, 52428800)
  f16* WT = (f16*)(ws + 52428800);         // [52428800, 52633600)
  f16* EF0 = (f16*)(ws + 52633600);        // [52633600, 55255040)
  float* att = (float*)(ws + 55255040);    // [55255040, 60497920)
  float* ef = (float*)(ws + 60497920);     // [60497920, 65478656)
  float* sc = (float*)(ws + 65478656);     // 4096*4
  float* pp = (float*)(ws + 65495040);     // 64*304*4

  hipLaunchKernelGGL(k01_prep, dim3(656), dim3(256), 0, stream, X, WATT, XT, WT);
  hipLaunchKernelGGL(k2_bigmm, dim3(512), dim3(512), 0, stream, INC, XT, Zp);
  hipLaunchKernelGGL(k2s_sum, dim3(640), dim3(256), 0, stream, Zp, EF0);
  hipLaunchKernelGGL(k2b_att, dim3(64), dim3(256), 0, stream, EF0, WT, att);
  hipLaunchKernelGGL(k3_edge, dim3(256), dim3(256), 0, stream, att, EF0, EFEATS,
                     WPROJ, ALPHA, ECATT, ef, sc);
  hipLaunchKernelGGL(k4ab_pool, dim3(64), dim3(256), 0, stream, sc, ef, pp);
  hipLaunchKernelGGL(k4c_final, dim3(1), dim3(320), 0, stream, pp, ECWP, ECB, FCW,
                     FCB, (float*)d_out);
}

// Round 15
// 238.208 us; speedup vs baseline: 1.1011x; 1.0993x over previous
//
#include <hip/hip_runtime.h>
#include <math.h>

typedef _Float16 f16;
typedef _Float16 f16x8 __attribute__((ext_vector_type(8)));
typedef _Float16 f16x4 __attribute__((ext_vector_type(4)));
typedef __fp16 fp16x2 __attribute__((ext_vector_type(2)));
typedef float f32x4 __attribute__((ext_vector_type(4)));
typedef float f32x16 __attribute__((ext_vector_type(16)));

#define NM 16384    // nodes (K of big GEMM)
#define NE 4096     // hyperedges
#define ND 300      // feature dim
#define DP 320      // padded feature dim
#define PS 1310720  // per-partial f16 elements (4096*320)

#define GLOAD_LDS16(gsrc, ldst)                                              \
  __builtin_amdgcn_global_load_lds(                                          \
      (__attribute__((address_space(1))) void*)(gsrc),                       \
      (__attribute__((address_space(3))) void*)(ldst), 16, 0, 0)

#define K2WAIT(N) asm volatile("s_waitcnt vmcnt(" #N ") lgkmcnt(0)" ::: "memory")
#define K2BAR()                                        \
  do {                                                 \
    asm volatile("" ::: "memory");                     \
    __builtin_amdgcn_s_barrier();                      \
    asm volatile("" ::: "memory");                     \
  } while (0)
#define K2BARW()                                       \
  do {                                                 \
    asm volatile("s_waitcnt lgkmcnt(0)" ::: "memory"); \
    __builtin_amdgcn_s_barrier();                      \
    asm volatile("" ::: "memory");                     \
  } while (0)

// ---------------------------------------------------------------- k01: X -> XT (f16, padded) + W_att^T -> f16
__global__ __launch_bounds__(256) void k01_prep(const float* __restrict__ X,
                                                const float* __restrict__ Watt,
                                                f16* __restrict__ XT,
                                                f16* __restrict__ WT) {
  __shared__ f16 tile[64][324];
  const int bx = blockIdx.x;
  if (bx < 256) {
    int m0 = bx * 64;
    for (int idx = threadIdx.x; idx < 64 * 80; idx += 256) {
      int m = idx / 80, q = idx % 80;
      int d = q * 4;
      float4 v = make_float4(0.f, 0.f, 0.f, 0.f);
      if (d < ND) v = *(const float4*)(X + (size_t)(m0 + m) * ND + d);
      tile[m][d] = (f16)v.x; tile[m][d + 1] = (f16)v.y;
      tile[m][d + 2] = (f16)v.z; tile[m][d + 3] = (f16)v.w;
    }
    __syncthreads();
    for (int idx = threadIdx.x; idx < DP * 8; idx += 256) {
      int d = idx >> 3, part = idx & 7;
      f16x8 hv;
#pragma unroll
      for (int i = 0; i < 8; ++i) hv[i] = tile[part * 8 + i][d];
      *(f16x8*)(XT + (size_t)d * NM + m0 + part * 8) = hv;
    }
  } else {
    int idx = (bx - 256) * 256 + threadIdx.x;
    if (idx < DP * DP) {
      int j = idx / DP, d = idx % DP;
      float v = (j < ND && d < ND) ? Watt[d * ND + j] : 0.f;
      WT[(size_t)j * DP + d] = (f16)v;
    }
  }
}

// ---------------------------------------------------------------- k2 v10 (reverted, R11-proven): EF0 = inc^T @ X
// block 128e x 320j x BK32, 256 thr / 4 waves (2we x 2wj), wave 64e x 160j.
// 77.8 KB LDS -> 2 independent blocks/CU (two barrier domains = overlap).
// grid 512 = 32 eb x 16 kb, xcd = kb&7. B-ring-3 + A-ring-2, implicit vmcnt.
// LDS: B @ 0/20480/40960 (320 rows x 64B); A @ 61440/69632 (128 rows x 64B)
__global__ __launch_bounds__(256, 2) void k2_bigmm(const float* __restrict__ inc,
                                                   const f16* __restrict__ XT,
                                                   f16* __restrict__ Zp) {
  __shared__ __align__(16) char lds[77824];
  const int t = threadIdx.x, lane = t & 63, wid = t >> 6;
  const int bx = blockIdx.x;
  const int kb = (bx & 7) | (((bx >> 3) & 1) << 3);
  const int eb = bx >> 4;
  const int e0 = eb * 128;
  const size_t kbase = (size_t)kb * 1024;
  f16* __restrict__ Zout = Zp + (size_t)kb * PS;

  const int we = wid >> 1, wj = wid & 1;
  const int l31 = lane & 31, oct = lane >> 5;
  int sl[2];
#pragma unroll
  for (int kk = 0; kk < 2; ++kk)
    sl[kk] = (((kk * 2 + oct) ^ ((l31 >> 1) & 3)) & 3) << 4;
  const int arow = (we * 64 + l31) * 64;
  const int brow = (wj * 160 + l31) * 64;
  // A staging: lane ep -> e-pair {2ep, 2ep+1}; kq = k-chunk of 8
  const int ep = t & 63, kq = t >> 6;
  const int sA = (kq ^ (ep & 3)) & 3;
  const int wa0 = 61440 + ep * 128 + sA * 16;  // row 2ep; row 2ep+1 at +64
  const float* pA = inc + (kbase + kq * 8) * NE + e0 + 2 * ep;
  const int br = wid * 80 + (lane >> 2);
  const f16* pB = XT + (size_t)br * NM + kbase + 8 * ((lane & 3) ^ ((lane >> 3) & 3));

  float2 rA0[8], rA1[8];
  f32x16 acc[2][5];
#pragma unroll
  for (int me = 0; me < 2; ++me)
#pragma unroll
    for (int f = 0; f < 5; ++f)
#pragma unroll
      for (int r = 0; r < 16; ++r) acc[me][f][r] = 0.f;

#define LOADA(R)                                                               \
  {                                                                            \
    _Pragma("unroll") for (int i = 0; i < 8; ++i)                              \
        R[i] = *(const float2*)(pA + (size_t)i * NE);                          \
    pA += (size_t)32 * NE;                                                     \
  }
#define DMAB(S)                                                                \
  {                                                                            \
    _Pragma("unroll") for (int i = 0; i < 5; ++i) {                            \
      GLOAD_LDS16(pB + (size_t)(i * 16) * NM,                                  \
                  lds + (S)*20480 + wid * 5120 + i * 1024);                    \
    }                                                                          \
    pB += 32;                                                                  \
  }
#define WRITEA(R, S)                                                           \
  {                                                                            \
    union { fp16x2 h; uint32_t u; } ux_[4], uy_[4];                            \
    _Pragma("unroll") for (int z = 0; z < 4; ++z) {                            \
      ux_[z].h = __builtin_amdgcn_cvt_pkrtz(R[2 * z].x, R[2 * z + 1].x);       \
      uy_[z].h = __builtin_amdgcn_cvt_pkrtz(R[2 * z].y, R[2 * z + 1].y);       \
    }                                                                          \
    *(uint4*)(lds + wa0 + (S)*8192) =                                          \
        make_uint4(ux_[0].u, ux_[1].u, ux_[2].u, ux_[3].u);                    \
    *(uint4*)(lds + wa0 + 64 + (S)*8192) =                                     \
        make_uint4(uy_[0].u, uy_[1].u, uy_[2].u, uy_[3].u);                    \
  }
#define COMPUTE(BS, AS)                                                        \
  {                                                                            \
    __builtin_amdgcn_s_setprio(1);                                             \
    _Pragma("unroll") for (int kk = 0; kk < 2; ++kk) {                         \
      f16x8 a0_ = *(const f16x8*)(lds + 61440 + (AS)*8192 + arow + sl[kk]);    \
      f16x8 a1_ = *(const f16x8*)(lds + 61440 + (AS)*8192 + arow + 2048 + sl[kk]); \
      _Pragma("unroll") for (int f = 0; f < 5; ++f) {                          \
        f16x8 b_ = *(const f16x8*)(lds + (BS)*20480 + brow + f * 2048 + sl[kk]); \
        acc[0][f] = __builtin_amdgcn_mfma_f32_32x32x16_f16(a0_, b_, acc[0][f], 0, 0, 0); \
        acc[1][f] = __builtin_amdgcn_mfma_f32_32x32x16_f16(a1_, b_, acc[1][f], 0, 0, 0); \
      }                                                                        \
    }                                                                          \
    __builtin_amdgcn_s_setprio(0);                                             \
  }
// BODY(tt): stage B(tt+2), load A(tt+2), write A(tt+1); barrier; compute tt.
#define BODY(BSTG, BCMP, AW, AC, RL, RW)                                       \
  DMAB(BSTG);                                                                  \
  LOADA(RL);                                                                   \
  WRITEA(RW, AW); /* implicit vmcnt drains A(tt+1) => B(tt+1),B(tt) resident */\
  K2BARW();                                                                    \
  COMPUTE(BCMP, AC);                                                           \
  K2BAR();

  // prologue
  LOADA(rA0);        // A(0)
  DMAB(0);           // B(0)
  WRITEA(rA0, 0);    // A(0) -> Abuf0 (implicit wait A(0))
  LOADA(rA1);        // A(1)
  DMAB(1);           // B(1)
  BODY(2, 0, 1, 0, rA0, rA1);   // tt=0

  for (int it = 0; it < 4; ++it) {  // tt = 1..24
    BODY(0, 1, 0, 1, rA1, rA0);     // tt%6=1
    BODY(1, 2, 1, 0, rA0, rA1);     // 2
    BODY(2, 0, 0, 1, rA1, rA0);     // 3
    BODY(0, 1, 1, 0, rA0, rA1);     // 4
    BODY(1, 2, 0, 1, rA1, rA0);     // 5
    BODY(2, 0, 1, 0, rA0, rA1);     // 0
  }
  BODY(0, 1, 0, 1, rA1, rA0);  // tt=25
  BODY(1, 2, 1, 0, rA0, rA1);  // 26
  BODY(2, 0, 0, 1, rA1, rA0);  // 27
  BODY(0, 1, 1, 0, rA0, rA1);  // 28
  BODY(1, 2, 0, 1, rA1, rA0);  // 29  (loads A(31) -> rA1, writes A(30) -> buf0)
  // tail: write A(31) (held in rA1), drain everything
  WRITEA(rA1, 1);
  K2WAIT(0);
  K2BAR();
  COMPUTE(0, 0);   // step 30: B 30%3=0, A 30&1=0
  K2BAR();
  COMPUTE(1, 1);   // step 31: B 31%3=1, A 31&1=1

  // epilogue: f16 partial store (C/D: col=lane&31 -> j, row=(r&3)+8*(r>>2)+4*oct -> e)
#pragma unroll
  for (int me = 0; me < 2; ++me)
#pragma unroll
    for (int f = 0; f < 5; ++f) {
      int jg = wj * 160 + f * 32 + l31;
      int ebase = e0 + we * 64 + me * 32 + 4 * oct;
#pragma unroll
      for (int r = 0; r < 16; ++r) {
        int eg = ebase + (r & 3) + 8 * (r >> 2);
        Zout[(size_t)eg * DP + jg] = (f16)acc[me][f][r];
      }
    }
#undef LOADA
#undef DMAB
#undef WRITEA
#undef COMPUTE
#undef BODY
}

// ---------------------------------------------------------------- k2s: sum 16 f16 partials -> EF0 (f16), full-BW grid
__global__ __launch_bounds__(256) void k2s_sum(const f16* __restrict__ Zp,
                                               f16* __restrict__ EF0) {
  const size_t idx = ((size_t)blockIdx.x * 256 + threadIdx.x) * 8;
  float s[8];
#pragma unroll
  for (int z = 0; z < 8; ++z) s[z] = 0.f;
#pragma unroll
  for (int p = 0; p < 16; ++p) {
    f16x8 v = *(const f16x8*)(Zp + (size_t)p * PS + idx);
#pragma unroll
    for (int z = 0; z < 8; ++z) s[z] += (float)v[z];
  }
  f16x8 o;
#pragma unroll
  for (int z = 0; z < 8; ++z) o[z] = (f16)s[z];
  *(f16x8*)(EF0 + idx) = o;
}

// ---------------------------------------------------------------- k2b: att = EF0 @ W_att (f32 out), 64 blocks x 64e
// LDS: Bbuf[2] @ 0/20480 (320 rows x 64B); Abuf[2] @ 40960/45056 (64 rows x 64B)
__global__ __launch_bounds__(256, 1) void k2b_att(const f16* __restrict__ EF0,
                                                  const f16* __restrict__ WT,
                                                  float* __restrict__ att) {
  __shared__ __align__(16) char lds[49152];
  const int t = threadIdx.x, lane = t & 63, wid = t >> 6;
  const int e0 = blockIdx.x * 64;
  const int we = wid >> 1, wj = wid & 1;
  const int l31 = lane & 31, oct = lane >> 5;
  int sl[2];
#pragma unroll
  for (int kk = 0; kk < 2; ++kk)
    sl[kk] = (((kk * 2 + oct) ^ ((l31 >> 1) & 3)) & 3) << 4;
  const int arow = (we * 32 + l31) * 64;
  const int brow = (wj * 160 + l31) * 64;
  const int srcsw = 8 * ((lane & 3) ^ ((lane >> 3) & 3));
  const f16* pA = EF0 + (size_t)(e0 + wid * 16 + (lane >> 2)) * DP + srcsw;
  const f16* pB = WT + (size_t)(wid * 80 + (lane >> 2)) * DP + srcsw;

  f32x16 acc[5];
#pragma unroll
  for (int f = 0; f < 5; ++f)
#pragma unroll
    for (int r = 0; r < 16; ++r) acc[f][r] = 0.f;

#define STAGE2(S)                                                              \
  {                                                                            \
    GLOAD_LDS16(pA, lds + 40960 + (S)*4096 + wid * 1024);                      \
    pA += 32;                                                                  \
    _Pragma("unroll") for (int i = 0; i < 5; ++i) {                            \
      GLOAD_LDS16(pB + (size_t)(i * 16) * DP,                                  \
                  lds + (S)*20480 + wid * 5120 + i * 1024);                    \
    }                                                                          \
    pB += 32;                                                                  \
  }
#define COMPUTE2(S)                                                            \
  {                                                                            \
    _Pragma("unroll") for (int kk = 0; kk < 2; ++kk) {                         \
      f16x8 a_ = *(const f16x8*)(lds + 40960 + (S)*4096 + arow + sl[kk]);      \
      _Pragma("unroll") for (int f = 0; f < 5; ++f) {                          \
        f16x8 b_ = *(const f16x8*)(lds + (S)*20480 + brow + f * 2048 + sl[kk]); \
        acc[f] = __builtin_amdgcn_mfma_f32_32x32x16_f16(a_, b_, acc[f], 0, 0, 0); \
      }                                                                        \
    }                                                                          \
  }

  STAGE2(0);
  STAGE2(1);
  K2WAIT(6);
  K2BAR();
  for (int tt = 0; tt < 8; ++tt) {
    COMPUTE2(tt & 1);
    K2BAR();
    STAGE2(tt & 1);
    K2WAIT(6);
    K2BAR();
  }
  COMPUTE2(0);
  K2BAR();
  K2WAIT(0);
  COMPUTE2(1);

#pragma unroll
  for (int f = 0; f < 5; ++f) {
    int jg = wj * 160 + f * 32 + l31;
    int ebase = e0 + we * 32 + 4 * oct;
#pragma unroll
    for (int r = 0; r < 16; ++r) {
      int eg = ebase + (r & 3) + 8 * (r >> 2);
      att[(size_t)eg * DP + jg] = acc[f][r];
    }
  }
#undef STAGE2
#undef COMPUTE2
}

// ---------------------------------------------------------------- k3: softmax(att) weights EF0 + projection
__global__ __launch_bounds__(256) void k3_edge(const float* __restrict__ att,
                                               const f16* __restrict__ EF0,
                                               const float* __restrict__ edge_feats,
                                               const float* __restrict__ Wproj,
                                               const float* __restrict__ alphaP,
                                               const float* __restrict__ ecWatt,
                                               float* __restrict__ ef,
                                               float* __restrict__ scores) {
  __shared__ float efw[16][304];
  const int t = threadIdx.x, lane = t & 63, w = t >> 6;
  const int e0 = blockIdx.x * 16;
  for (int el = 0; el < 4; ++el) {
    int e = e0 + w * 4 + el;
    const size_t ro = (size_t)e * DP;
    float p[5];
    float mx = -1e30f;
#pragma unroll
    for (int u = 0; u < 5; ++u) {
      int d = u * 64 + lane;
      p[u] = (d < ND) ? att[ro + d] : -1e30f;
      mx = fmaxf(mx, p[u]);
    }
    for (int o = 32; o; o >>= 1) mx = fmaxf(mx, __shfl_xor(mx, o));
    float s = 0.f;
#pragma unroll
    for (int u = 0; u < 5; ++u) {
      int d = u * 64 + lane;
      float pe = (d < ND) ? expf(p[u] - mx) : 0.f;
      p[u] = pe;
      s += pe;
    }
    for (int o = 32; o; o >>= 1) s += __shfl_xor(s, o);
    float inv = 1.f / s;
#pragma unroll
    for (int u = 0; u < 5; ++u) {
      int d = u * 64 + lane;
      if (d < 304)
        efw[w * 4 + el][d] = (d < ND) ? (float)EF0[ro + d] * p[u] * inv : 0.f;
    }
  }
  __syncthreads();
  const int jl = lane & 15, kc = lane >> 4;
  const float alpha = alphaP[0];
  float acc[4][19];
#pragma unroll
  for (int ei = 0; ei < 4; ++ei)
#pragma unroll
    for (int jj = 0; jj < 19; ++jj) acc[ei][jj] = 0.f;
  const int d0 = kc * 75;
  const float* efw0 = &efw[w * 4 + 0][0];
  const float* efw1 = &efw[w * 4 + 1][0];
  const float* efw2 = &efw[w * 4 + 2][0];
  const float* efw3 = &efw[w * 4 + 3][0];
  for (int dd = 0; dd < 75; ++dd) {
    int d = d0 + dd;
    const float* wr = Wproj + (size_t)d * ND + jl;
    float w0 = efw0[d], w1 = efw1[d], w2 = efw2[d], w3 = efw3[d];
#pragma unroll
    for (int jj = 0; jj < 19; ++jj) {
      int j = jl + jj * 16;
      float wv = (j < ND) ? wr[jj * 16] : 0.f;
      acc[0][jj] += w0 * wv;
      acc[1][jj] += w1 * wv;
      acc[2][jj] += w2 * wv;
      acc[3][jj] += w3 * wv;
    }
  }
#pragma unroll
  for (int ei = 0; ei < 4; ++ei)
#pragma unroll
    for (int jj = 0; jj < 19; ++jj) {
      acc[ei][jj] += __shfl_xor(acc[ei][jj], 16);
      acc[ei][jj] += __shfl_xor(acc[ei][jj], 32);
    }
  float scp[4] = {0.f, 0.f, 0.f, 0.f};
#pragma unroll
  for (int ei = 0; ei < 4; ++ei) {
    int e = e0 + w * 4 + ei;
#pragma unroll
    for (int jj = 0; jj < 19; ++jj) {
      int j = jl + jj * 16;
      float v = 0.f;
      if (j < ND) {
        v = alpha * edge_feats[(size_t)e * ND + j] + (1.f - alpha) * acc[ei][jj];
        scp[ei] += v * ecWatt[j];
      }
      if (kc == 0) ef[(size_t)e * 304 + j] = v;
    }
  }
#pragma unroll
  for (int ei = 0; ei < 4; ++ei)
    for (int o = 8; o; o >>= 1) scp[ei] += __shfl_xor(scp[ei], o);
  if (lane == 0) {
#pragma unroll
    for (int ei = 0; ei < 4; ++ei) scores[e0 + w * 4 + ei] = scp[ei];
  }
}

// ---------------------------------------------------------------- k4ab: per-block softmax recompute + weighted pooling
__global__ __launch_bounds__(256) void k4ab_pool(const float* __restrict__ sc,
                                                 const float* __restrict__ ef,
                                                 float* __restrict__ pp) {
  __shared__ float redm[4];
  __shared__ float reds[4];
  __shared__ float wsh[64];
  const int t = threadIdx.x, lane = t & 63, w = t >> 6;
  float v[16];
  float mx = -1e30f;
#pragma unroll
  for (int u = 0; u < 16; ++u) {
    v[u] = sc[t + u * 256];
    mx = fmaxf(mx, v[u]);
  }
  for (int o = 32; o; o >>= 1) mx = fmaxf(mx, __shfl_xor(mx, o));
  if (lane == 0) redm[w] = mx;
  __syncthreads();
  float m2 = fmaxf(fmaxf(redm[0], redm[1]), fmaxf(redm[2], redm[3]));
  float s = 0.f;
#pragma unroll
  for (int u = 0; u < 16; ++u) s += expf(v[u] - m2);
  for (int o = 32; o; o >>= 1) s += __shfl_xor(s, o);
  if (lane == 0) reds[w] = s;
  __syncthreads();
  float inv = 1.f / (reds[0] + reds[1] + reds[2] + reds[3]);
  const int e0 = blockIdx.x * 64;
  if (t < 64) wsh[t] = expf(sc[e0 + t] - m2) * inv;
  __syncthreads();
  for (int j = t; j < 304; j += 256) {
    float acc = 0.f;
#pragma unroll 8
    for (int e = 0; e < 64; ++e) acc += wsh[e] * ef[(size_t)(e0 + e) * 304 + j];
    pp[blockIdx.x * 304 + j] = acc;
  }
}

// ---------------------------------------------------------------- k4c: final reduce + two matvecs -> 3 logits
__global__ __launch_bounds__(320) void k4c_final(const float* __restrict__ pp,
                                                 const float* __restrict__ ecWp,
                                                 const float* __restrict__ ecb,
                                                 const float* __restrict__ fcW,
                                                 const float* __restrict__ fcb,
                                                 float* __restrict__ out) {
  __shared__ float pooled[304];
  __shared__ float o[304];
  const int t = threadIdx.x;
  if (t < 304) {
    float acc = 0.f;
#pragma unroll 8
    for (int b = 0; b < 64; ++b) acc += pp[b * 304 + t];
    pooled[t] = acc;
  }
  __syncthreads();
  if (t < ND) {
    float acc = ecb[t];
#pragma unroll 4
    for (int j = 0; j < ND; ++j) acc += pooled[j] * ecWp[(size_t)j * ND + t];
    o[t] = acc;
  }
  __syncthreads();
  if (t < 64) {
#pragma unroll
    for (int c = 0; c < 3; ++c) {
      float a = 0.f;
      for (int j2 = t; j2 < ND; j2 += 64) a += o[j2] * fcW[j2 * 3 + c];
      for (int off = 32; off; off >>= 1) a += __shfl_xor(a, off);
      if (t == 0) out[c] = a + fcb[c];
    }
  }
}

// ----------------------------------------------------------------
extern "C" void kernel_launch(void* const* d_in, const int* in_sizes, int n_in,
                              void* d_out, int out_size, void* d_ws, size_t ws_size,
                              hipStream_t stream) {
  const float* X = (const float*)d_in[0];
  const float* EFEATS = (const float*)d_in[1];
  const float* INC = (const float*)d_in[2];
  const float* WATT = (const float*)d_in[3];
  const float* WPROJ = (const float*)d_in[4];
  const float* ALPHA = (const float*)d_in[5];
  const float* ECATT = (const float*)d_in[6];
  const float* ECWP = (const float*)d_in[7];
  const float* ECB = (const float*)d_in[8];
  const float* FCW = (const float*)d_in[9];
  const float* FCB = (const float*)d_in[10];

  char* ws = (char*)d_ws;
  f16* XT = (f16*)(ws);                    // [0, 10485760)
  f16* Zp = (f16*)(ws + 10485760);         // 16 x 2621440 B -> [10485760, 52428800)
  f16* WT = (f16*)(ws + 52428800);         // [52428800, 52633600)
  f16* EF0 = (f16*)(ws + 52633600);        // [52633600, 55255040)
  float* att = (float*)(ws + 55255040);    // [55255040, 60497920)
  float* ef = (float*)(ws + 60497920);     // [60497920, 65478656)
  float* sc = (float*)(ws + 65478656);     // 4096*4
  float* pp = (float*)(ws + 65495040);     // 64*304*4

  hipLaunchKernelGGL(k01_prep, dim3(656), dim3(256), 0, stream, X, WATT, XT, WT);
  hipLaunchKernelGGL(k2_bigmm, dim3(512), dim3(256), 0, stream, INC, XT, Zp);
  hipLaunchKernelGGL(k2s_sum, dim3(640), dim3(256), 0, stream, Zp, EF0);
  hipLaunchKernelGGL(k2b_att, dim3(64), dim3(256), 0, stream, EF0, WT, att);
  hipLaunchKernelGGL(k3_edge, dim3(256), dim3(256), 0, stream, att, EF0, EFEATS,
                     WPROJ, ALPHA, ECATT, ef, sc);
  hipLaunchKernelGGL(k4ab_pool, dim3(64), dim3(256), 0, stream, sc, ef, pp);
  hipLaunchKernelGGL(k4c_final, dim3(1), dim3(320), 0, stream, pp, ECWP, ECB, FCW,
                     FCB, (float*)d_out);
}